// Round 12
// baseline (296.583 us; speedup 1.0000x reference)
//
#include <hip/hip_runtime.h>

typedef unsigned short u16;
typedef __attribute__((ext_vector_type(8))) short bf16x8;
typedef __attribute__((ext_vector_type(4))) float f32x4;
typedef __attribute__((ext_vector_type(4))) unsigned short u16x4;

__device__ __forceinline__ u16 f2bf(float f) {
  union { float f; unsigned u; } v; v.f = f;
  return (u16)((v.u + 0x7FFFu + ((v.u >> 16) & 1u)) >> 16);
}

__device__ __forceinline__ void gload16(const u16* g, u16* l) {
  __builtin_amdgcn_global_load_lds((const __attribute__((address_space(1))) void*)g,
                                   (__attribute__((address_space(3))) void*)l, 16, 0, 0);
}

// ---------------- fp32 -> bf16 convert (5 tensors fused) ----------------
__global__ __launch_bounds__(256) void k_f2bf5(
    const float* __restrict__ i0, const float* __restrict__ i1, const float* __restrict__ i2,
    const float* __restrict__ i3, const float* __restrict__ i4,
    u16* o0, u16* o1, u16* o2, u16* o3, u16* o4, int n4x, int n4w) {
  const int seg = blockIdx.y;
  const float* in = (seg == 0) ? i0 : (seg == 1) ? i1 : (seg == 2) ? i2 : (seg == 3) ? i3 : i4;
  u16* out = (seg == 0) ? o0 : (seg == 1) ? o1 : (seg == 2) ? o2 : (seg == 3) ? o3 : o4;
  const int n4 = (seg == 0) ? n4x : n4w;
  int i = blockIdx.x * 256 + threadIdx.x;
  const int stride = gridDim.x * 256;
  for (; i < n4; i += stride) {
    const float4 v = ((const float4*)in)[i];
    u16x4 o;
    o.x = f2bf(v.x); o.y = f2bf(v.y); o.z = f2bf(v.z); o.w = f2bf(v.w);
    ((u16x4*)out)[i] = o;
  }
}

// ---------------- 128x128 GEMM, m97-structure + T2 swizzle + multi-block TLP ----------
template <int OUT_F32>
__global__ __launch_bounds__(256, 4) void k_gemm12(
    const u16* __restrict__ A, const u16* __restrict__ Bt,
    const float* __restrict__ b0, const float* __restrict__ b1, const float* __restrict__ b2,
    u16* __restrict__ C0, u16* __restrict__ C1, u16* __restrict__ C2,
    float* __restrict__ Cf, int NBM)
{
  __shared__ alignas(16) u16 As[8192];   // [128 rows][64 k], swizzled
  __shared__ alignas(16) u16 Bs[8192];

  const int tid = threadIdx.x;
  const int lane = tid & 63, wid = tid >> 6;
  const int fr = lane & 15, fg = lane >> 4;
  const int wr = wid >> 1, wc = wid & 1;

  const int nblk = gridDim.x;
  const int q = nblk >> 3, r = nblk & 7;
  const int xcd = blockIdx.x & 7, lid = blockIdx.x >> 3;
  const int wgid = (xcd < r ? xcd * (q + 1) : r * (q + 1) + (xcd - r) * q) + lid;
  const int mb = wgid % NBM, nb = wgid / NBM;
  const long row0 = (long)mb * 128;
  const long col0 = (long)nb * 128;

  int sRow[4], sCol[4];
#pragma unroll
  for (int i = 0; i < 4; ++i) {
    const int g = (wid * 4 + i) * 64 + lane;
    sRow[i] = g >> 3;
    sCol[i] = ((g & 7) ^ (sRow[i] & 7)) << 3;
  }

  const int sw = fr & 7;
  const int aBase = (wr * 64 + fr) * 64;
  const int bBase = (wc * 64 + fr) * 64;
  const int pc0 = (fg ^ sw) << 3;
  const int pc1 = ((4 + fg) ^ sw) << 3;

  f32x4 acc[4][4] = {};

#pragma unroll 1
  for (int t = 0; t < 32; ++t) {
    if (t) __syncthreads();
    const long k0 = (long)t << 6;
#pragma unroll
    for (int i = 0; i < 4; ++i) {
      gload16(A  + (row0 + sRow[i]) * 2048L + k0 + sCol[i], &As[(wid * 4 + i) * 512]);
      gload16(Bt + (col0 + sRow[i]) * 2048L + k0 + sCol[i], &Bs[(wid * 4 + i) * 512]);
    }
    __syncthreads();

#pragma unroll
    for (int kc = 0; kc < 2; ++kc) {
      const int pc = kc ? pc1 : pc0;
      bf16x8 a[4], b[4];
#pragma unroll
      for (int i = 0; i < 4; ++i) {
        a[i] = *(const bf16x8*)&As[aBase + i * 1024 + pc];
        b[i] = *(const bf16x8*)&Bs[bBase + i * 1024 + pc];
      }
#pragma unroll
      for (int i = 0; i < 4; ++i)
#pragma unroll
        for (int j = 0; j < 4; ++j)
          acc[i][j] = __builtin_amdgcn_mfma_f32_16x16x32_bf16(a[i], b[j], acc[i][j], 0, 0, 0);
    }
  }

  const int seg = (int)(col0 >> 11);
  const long colL = col0 & 2047;
  const float* bp = (seg == 0) ? b0 : (seg == 1) ? b1 : b2;
  u16* Cb = (seg == 0) ? C0 : (seg == 1) ? C1 : C2;
#pragma unroll
  for (int j = 0; j < 4; ++j) {
    const long cN = colL + wc * 64 + j * 16 + fr;
    const float bv = bp[cN];
#pragma unroll
    for (int i = 0; i < 4; ++i) {
      const long rM = row0 + wr * 64 + i * 16 + fg * 4;
#pragma unroll
      for (int reg = 0; reg < 4; ++reg) {
        const float v = acc[i][j][reg] + bv;
        if (OUT_F32) Cf[(rM + reg) * 2048 + cN] = v;
        else         Cb[(rM + reg) * 2048 + cN] = f2bf(v);
      }
    }
  }
}

// ---------------- V transpose: V[b][s][h*128+d] -> Vt[(b*16+h)*128+d][s] ----------------
__global__ __launch_bounds__(256) void k_transpose_v(const u16* __restrict__ V,
                                                     u16* __restrict__ Vt) {
  __shared__ u16 t[64][68];
  const int bh = blockIdx.z;
  const long s0 = (long)blockIdx.x * 64;
  const long d0 = (long)blockIdx.y * 64;
  const int tid = threadIdx.x;
  const long rowbase = (long)(bh >> 4) * 2048;
  const int hcol = (bh & 15) * 128;
#pragma unroll
  for (int i = 0; i < 4; ++i) {
    const int v = tid + i * 256;
    const int r = v >> 4, c4 = (v & 15) << 2;
    const u16x4 val = *(const u16x4*)&V[(rowbase + s0 + r) * 2048 + hcol + d0 + c4];
    *(u16x4*)&t[r][c4] = val;
  }
  __syncthreads();
#pragma unroll
  for (int i = 0; i < 4; ++i) {
    const int v = tid + i * 256;
    const int dr = v >> 4, s4 = (v & 15) << 2;
    u16x4 o;
    o.x = t[s4 + 0][dr]; o.y = t[s4 + 1][dr]; o.z = t[s4 + 2][dr]; o.w = t[s4 + 3][dr];
    *(u16x4*)&Vt[((long)bh * 128 + d0 + dr) * 2048 + s0 + s4] = o;
  }
}

// ---------------- causal flash attention: QBLK=128, 32 q-rows/wave ----------------
// Each kf/vf LDS read feeds TWO MFMAs (2 q-frags share K; 2 P-frags share V) ->
// halves per-MFMA LDS-unit traffic (the measured binding pipe). 4 waves, KVBLK=64,
// single-buffered K/V+P (50.4 KB), 2 blocks/CU; per-step drain covered by the
// other resident block. Complementary dispatch pairing: qblk = c<8 ? 15-c : c-8
// so co-resident blocks sum to ~34 steps. XCD map: blocks of one bh share L&7.
__global__ __launch_bounds__(256, 2) void k_flash_attn(
    const u16* __restrict__ Q, const u16* __restrict__ K, const u16* __restrict__ Vt,
    u16* __restrict__ O)
{
  __shared__ alignas(16) u16 Kt[8192];        // [64 kv][128 d], swizzled
  __shared__ alignas(16) u16 Vtt[8192];       // [128 d][64 s], swizzled
  __shared__ alignas(16) u16 Plds[4][32][72]; // per-wave P (32 q-rows x 64 kv)

  const int tid = threadIdx.x;
  const int lane = tid & 63, wid = tid >> 6;
  const int fr = lane & 15, fg = lane >> 4;

  const int L = blockIdx.x;
  const int bh = (L & 7) * 4 + ((L >> 3) & 3);
  const int c = L >> 5;                          // 0..15
  const int qblk = (c < 8) ? (15 - c) : (c - 8); // complementary pairing
  const int n = 2 * (qblk + 1);
  const int q_lo = qblk * 128 + wid * 32;        // wave's first q row (32 rows)

  const long rowbase = (long)(bh >> 4) * 2048;
  const int hcol = (bh & 15) * 128;
  const u16* Kg = K + rowbase * 2048 + hcol;
  const u16* Vg = Vt + (long)bh * 128 * 2048;
  const float scale2 = 0.08838834764831845f * 1.44269504089f;  // 1/sqrt(128)*log2(e)

  // staging: 1024 chunks per tile, 4/thread for each of K and V
  int kR[4], kC[4], vR[4], vC[4];
#pragma unroll
  for (int i = 0; i < 4; ++i) {
    const int g = (wid * 4 + i) * 64 + lane;
    kR[i] = g >> 4;                              // K: 16 chunks/row
    kC[i] = ((g & 15) ^ (kR[i] & 7)) << 3;
    vR[i] = g >> 3;                              // V: 8 chunks/row
    vC[i] = ((g & 7) ^ (vR[i] & 7)) << 3;
  }

  const int sw = fr & 7;
  int kbase[4], vbase[2];
#pragma unroll
  for (int cc = 0; cc < 4; ++cc) kbase[cc] = fr * 128 + (((cc * 4 + fg) ^ sw) << 3);
#pragma unroll
  for (int kc = 0; kc < 2; ++kc) vbase[kc] = fr * 64 + (((kc * 4 + fg) ^ sw) << 3);

  // Q fragments: 2 frags x 4 k-chunks (rows q_lo + f*16 + fr)
  bf16x8 qf[2][4];
#pragma unroll
  for (int f = 0; f < 2; ++f)
#pragma unroll
    for (int cc = 0; cc < 4; ++cc)
      qf[f][cc] = *(const bf16x8*)&Q[(rowbase + q_lo + f * 16 + fr) * 2048 + hcol + cc * 32 + fg * 8];

  f32x4 oacc[2][8] = {};
  float m_run[2][4], l_run[2][4];
#pragma unroll
  for (int f = 0; f < 2; ++f)
#pragma unroll
    for (int r = 0; r < 4; ++r) { m_run[f][r] = -1e30f; l_run[f][r] = 0.0f; }

  for (int j = 0; j < n; ++j) {
    if (j) __syncthreads();                     // readers of previous tile done
    const long kv = (long)j * 64;
#pragma unroll
    for (int i = 0; i < 4; ++i) {
      gload16(Kg + (kv + kR[i]) * 2048 + kC[i], &Kt[(wid * 4 + i) * 512]);
      gload16(Vg + (long)vR[i] * 2048 + kv + vC[i], &Vtt[(wid * 4 + i) * 512]);
    }
    __syncthreads();                            // drain covered by other resident block

    const int kvlo = j * 64;
    const bool skip = (kvlo >= q_lo + 32);      // tile fully above this wave's rows
    if (!skip) {
      const bool needmask = (kvlo + 63 > q_lo);

      // ---- QK^T: 16 kf reads feed 32 MFMAs ----
      f32x4 st[2][4] = {};
#pragma unroll
      for (int t = 0; t < 4; ++t)
#pragma unroll
        for (int cc = 0; cc < 4; ++cc) {
          const bf16x8 kf = *(const bf16x8*)&Kt[kbase[cc] + t * 2048];
          st[0][t] = __builtin_amdgcn_mfma_f32_16x16x32_bf16(qf[0][cc], kf, st[0][t], 0, 0, 0);
          st[1][t] = __builtin_amdgcn_mfma_f32_16x16x32_bf16(qf[1][cc], kf, st[1][t], 0, 0, 0);
        }

      // ---- scale/mask + row max ----
      float pmax[2][4];
#pragma unroll
      for (int f = 0; f < 2; ++f)
#pragma unroll
        for (int r = 0; r < 4; ++r) pmax[f][r] = -1e30f;
      if (needmask) {
#pragma unroll
        for (int f = 0; f < 2; ++f)
#pragma unroll
          for (int t = 0; t < 4; ++t) {
            const int kg = kvlo + t * 16 + fr;
#pragma unroll
            for (int r = 0; r < 4; ++r) {
              const int qg = q_lo + f * 16 + fg * 4 + r;
              const float v = (kg <= qg) ? st[f][t][r] * scale2 : -1e30f;
              st[f][t][r] = v;
              pmax[f][r] = fmaxf(pmax[f][r], v);
            }
          }
      } else {
#pragma unroll
        for (int f = 0; f < 2; ++f)
#pragma unroll
          for (int t = 0; t < 4; ++t)
#pragma unroll
            for (int r = 0; r < 4; ++r) {
              const float v = st[f][t][r] * scale2;
              st[f][t][r] = v;
              pmax[f][r] = fmaxf(pmax[f][r], v);
            }
      }
#pragma unroll
      for (int d = 1; d < 16; d <<= 1)
#pragma unroll
        for (int f = 0; f < 2; ++f)
#pragma unroll
          for (int r = 0; r < 4; ++r) pmax[f][r] = fmaxf(pmax[f][r], __shfl_xor(pmax[f][r], d));

      // ---- defer-max rescale (THR=8 log2 units) ----
      int ok = 1;
#pragma unroll
      for (int f = 0; f < 2; ++f)
#pragma unroll
        for (int r = 0; r < 4; ++r) ok &= (pmax[f][r] <= m_run[f][r] + 8.f);
      if (!__all(ok)) {
#pragma unroll
        for (int f = 0; f < 2; ++f)
#pragma unroll
          for (int r = 0; r < 4; ++r) {
            const float nm = fmaxf(m_run[f][r], pmax[f][r]);
            const float al = exp2f(m_run[f][r] - nm);
            l_run[f][r] *= al;
            m_run[f][r] = nm;
#pragma unroll
            for (int dt = 0; dt < 8; ++dt) oacc[f][dt][r] *= al;
          }
      }

      // ---- P = exp2(s-m), row sum ----
      float lsum[2][4] = {};
#pragma unroll
      for (int f = 0; f < 2; ++f)
#pragma unroll
        for (int t = 0; t < 4; ++t)
#pragma unroll
          for (int r = 0; r < 4; ++r) {
            const float p = exp2f(st[f][t][r] - m_run[f][r]);
            st[f][t][r] = p;
            lsum[f][r] += p;
          }
#pragma unroll
      for (int d = 1; d < 16; d <<= 1)
#pragma unroll
        for (int f = 0; f < 2; ++f)
#pragma unroll
          for (int r = 0; r < 4; ++r) lsum[f][r] += __shfl_xor(lsum[f][r], d);
#pragma unroll
      for (int f = 0; f < 2; ++f)
#pragma unroll
        for (int r = 0; r < 4; ++r) l_run[f][r] += lsum[f][r];

      // ---- P -> per-wave LDS (A-operand layout) ----
#pragma unroll
      for (int f = 0; f < 2; ++f)
#pragma unroll
        for (int t = 0; t < 4; ++t)
#pragma unroll
          for (int r = 0; r < 4; ++r)
            Plds[wid][f * 16 + fg * 4 + r][t * 16 + fr] = f2bf(st[f][t][r]);
      asm volatile("s_waitcnt lgkmcnt(0)" ::: "memory");
      __builtin_amdgcn_sched_barrier(0);

      // ---- O += P*V: 16 vf reads feed 32 MFMAs ----
#pragma unroll
      for (int kc = 0; kc < 2; ++kc) {
        const bf16x8 pf0 = *(const bf16x8*)&Plds[wid][fr][kc * 32 + fg * 8];
        const bf16x8 pf1 = *(const bf16x8*)&Plds[wid][16 + fr][kc * 32 + fg * 8];
#pragma unroll
        for (int dt = 0; dt < 8; ++dt) {
          const bf16x8 vf = *(const bf16x8*)&Vtt[vbase[kc] + dt * 1024];
          oacc[0][dt] = __builtin_amdgcn_mfma_f32_16x16x32_bf16(pf0, vf, oacc[0][dt], 0, 0, 0);
          oacc[1][dt] = __builtin_amdgcn_mfma_f32_16x16x32_bf16(pf1, vf, oacc[1][dt], 0, 0, 0);
        }
      }
    }
  }

  float inv[2][4];
#pragma unroll
  for (int f = 0; f < 2; ++f)
#pragma unroll
    for (int r = 0; r < 4; ++r) inv[f][r] = 1.0f / l_run[f][r];
#pragma unroll
  for (int f = 0; f < 2; ++f)
#pragma unroll
    for (int dt = 0; dt < 8; ++dt)
#pragma unroll
      for (int r = 0; r < 4; ++r)
        O[(rowbase + q_lo + f * 16 + fg * 4 + r) * 2048 + hcol + dt * 16 + fr] =
            f2bf(oacc[f][dt][r] * inv[f][r]);
}

extern "C" void kernel_launch(void* const* d_in, const int* in_sizes, int n_in,
                              void* d_out, int out_size, void* d_ws, size_t ws_size,
                              hipStream_t stream) {
  const float* x  = (const float*)d_in[0];
  const float* Wq = (const float*)d_in[1];
  const float* bq = (const float*)d_in[2];
  const float* Wk = (const float*)d_in[3];
  const float* bk = (const float*)d_in[4];
  const float* Wv = (const float*)d_in[5];
  const float* bv = (const float*)d_in[6];
  const float* Wo = (const float*)d_in[7];
  const float* bo = (const float*)d_in[8];
  float* out = (float*)d_out;

  char* ws = (char*)d_ws;
  const size_t SZ_X = 16777216;   // 8M bf16
  const size_t SZ_W = 8388608;    // 4M bf16
  u16* xb  = (u16*)(ws);
  u16* wqb = (u16*)(ws + SZ_X);                 // wq/wk/wv contiguous = [6144][2048]
  u16* wkb = (u16*)(ws + SZ_X + 1 * SZ_W);
  u16* wvb = (u16*)(ws + SZ_X + 2 * SZ_W);
  u16* wob = (u16*)(ws + SZ_X + 3 * SZ_W);
  u16* Qb  = (u16*)(ws + 1 * SZ_X + 4 * SZ_W);
  u16* Kb  = (u16*)(ws + 2 * SZ_X + 4 * SZ_W);
  u16* Vb  = (u16*)(ws + 3 * SZ_X + 4 * SZ_W);
  u16* Vtb = (u16*)(ws + 4 * SZ_X + 4 * SZ_W);
  u16* Ob  = Vb;   // V dead after transpose; reuse for attention output

  k_f2bf5<<<dim3(1024, 5), 256, 0, stream>>>(x, Wq, Wk, Wv, Wo,
                                             xb, wqb, wkb, wvb, wob,
                                             8388608 / 4, 4194304 / 4);

  // fused QKV: M=4096 x N=6144 x K=2048; 32x48 = 1536 blocks, ~4 blocks/CU resident
  k_gemm12<0><<<1536, 256, 0, stream>>>(xb, wqb, bq, bk, bv, Qb, Kb, Vb, nullptr, 32);

  k_transpose_v<<<dim3(32, 2, 32), 256, 0, stream>>>(Vb, Vtb);

  k_flash_attn<<<512, 256, 0, stream>>>(Qb, Kb, Vtb, Ob);

  // output projection (fp32 out): 32x16 = 512 blocks
  k_gemm12<1><<<512, 256, 0, stream>>>(Ob, wob, bo, bo, bo, nullptr, nullptr, nullptr, out, 32);
}

// Round 13
// 261.650 us; speedup vs baseline: 1.1335x; 1.1335x over previous
//
#include <hip/hip_runtime.h>

typedef unsigned short u16;
typedef __attribute__((ext_vector_type(8))) short bf16x8;
typedef __attribute__((ext_vector_type(4))) float f32x4;
typedef __attribute__((ext_vector_type(4))) unsigned short u16x4;

__device__ __forceinline__ u16 f2bf(float f) {
  union { float f; unsigned u; } v; v.f = f;
  return (u16)((v.u + 0x7FFFu + ((v.u >> 16) & 1u)) >> 16);
}

__device__ __forceinline__ void gload16(const u16* g, u16* l) {
  __builtin_amdgcn_global_load_lds((const __attribute__((address_space(1))) void*)g,
                                   (__attribute__((address_space(3))) void*)l, 16, 0, 0);
}

// ---------------- fp32 -> bf16 convert (5 tensors fused) ----------------
__global__ __launch_bounds__(256) void k_f2bf5(
    const float* __restrict__ i0, const float* __restrict__ i1, const float* __restrict__ i2,
    const float* __restrict__ i3, const float* __restrict__ i4,
    u16* o0, u16* o1, u16* o2, u16* o3, u16* o4, int n4x, int n4w) {
  const int seg = blockIdx.y;
  const float* in = (seg == 0) ? i0 : (seg == 1) ? i1 : (seg == 2) ? i2 : (seg == 3) ? i3 : i4;
  u16* out = (seg == 0) ? o0 : (seg == 1) ? o1 : (seg == 2) ? o2 : (seg == 3) ? o3 : o4;
  const int n4 = (seg == 0) ? n4x : n4w;
  int i = blockIdx.x * 256 + threadIdx.x;
  const int stride = gridDim.x * 256;
  for (; i < n4; i += stride) {
    const float4 v = ((const float4*)in)[i];
    u16x4 o;
    o.x = f2bf(v.x); o.y = f2bf(v.y); o.z = f2bf(v.z); o.w = f2bf(v.w);
    ((u16x4*)out)[i] = o;
  }
}

// ---------------- 128x128 GEMM, m97-structure + T2 swizzle + multi-block TLP ----------
template <int OUT_F32>
__global__ __launch_bounds__(256, 4) void k_gemm12(
    const u16* __restrict__ A, const u16* __restrict__ Bt,
    const float* __restrict__ b0, const float* __restrict__ b1, const float* __restrict__ b2,
    u16* __restrict__ C0, u16* __restrict__ C1, u16* __restrict__ C2,
    float* __restrict__ Cf, int NBM)
{
  __shared__ alignas(16) u16 As[8192];   // [128 rows][64 k], swizzled
  __shared__ alignas(16) u16 Bs[8192];

  const int tid = threadIdx.x;
  const int lane = tid & 63, wid = tid >> 6;
  const int fr = lane & 15, fg = lane >> 4;
  const int wr = wid >> 1, wc = wid & 1;

  const int nblk = gridDim.x;
  const int q = nblk >> 3, r = nblk & 7;
  const int xcd = blockIdx.x & 7, lid = blockIdx.x >> 3;
  const int wgid = (xcd < r ? xcd * (q + 1) : r * (q + 1) + (xcd - r) * q) + lid;
  const int mb = wgid % NBM, nb = wgid / NBM;
  const long row0 = (long)mb * 128;
  const long col0 = (long)nb * 128;

  int sRow[4], sCol[4];
#pragma unroll
  for (int i = 0; i < 4; ++i) {
    const int g = (wid * 4 + i) * 64 + lane;
    sRow[i] = g >> 3;
    sCol[i] = ((g & 7) ^ (sRow[i] & 7)) << 3;
  }

  const int sw = fr & 7;
  const int aBase = (wr * 64 + fr) * 64;
  const int bBase = (wc * 64 + fr) * 64;
  const int pc0 = (fg ^ sw) << 3;
  const int pc1 = ((4 + fg) ^ sw) << 3;

  f32x4 acc[4][4] = {};

#pragma unroll 1
  for (int t = 0; t < 32; ++t) {
    if (t) __syncthreads();
    const long k0 = (long)t << 6;
#pragma unroll
    for (int i = 0; i < 4; ++i) {
      gload16(A  + (row0 + sRow[i]) * 2048L + k0 + sCol[i], &As[(wid * 4 + i) * 512]);
      gload16(Bt + (col0 + sRow[i]) * 2048L + k0 + sCol[i], &Bs[(wid * 4 + i) * 512]);
    }
    __syncthreads();

#pragma unroll
    for (int kc = 0; kc < 2; ++kc) {
      const int pc = kc ? pc1 : pc0;
      bf16x8 a[4], b[4];
#pragma unroll
      for (int i = 0; i < 4; ++i) {
        a[i] = *(const bf16x8*)&As[aBase + i * 1024 + pc];
        b[i] = *(const bf16x8*)&Bs[bBase + i * 1024 + pc];
      }
#pragma unroll
      for (int i = 0; i < 4; ++i)
#pragma unroll
        for (int j = 0; j < 4; ++j)
          acc[i][j] = __builtin_amdgcn_mfma_f32_16x16x32_bf16(a[i], b[j], acc[i][j], 0, 0, 0);
    }
  }

  const int seg = (int)(col0 >> 11);
  const long colL = col0 & 2047;
  const float* bp = (seg == 0) ? b0 : (seg == 1) ? b1 : b2;
  u16* Cb = (seg == 0) ? C0 : (seg == 1) ? C1 : C2;
#pragma unroll
  for (int j = 0; j < 4; ++j) {
    const long cN = colL + wc * 64 + j * 16 + fr;
    const float bv = bp[cN];
#pragma unroll
    for (int i = 0; i < 4; ++i) {
      const long rM = row0 + wr * 64 + i * 16 + fg * 4;
#pragma unroll
      for (int reg = 0; reg < 4; ++reg) {
        const float v = acc[i][j][reg] + bv;
        if (OUT_F32) Cf[(rM + reg) * 2048 + cN] = v;
        else         Cb[(rM + reg) * 2048 + cN] = f2bf(v);
      }
    }
  }
}

// ---------------- V transpose: V[b][s][h*128+d] -> Vt[(b*16+h)*128+d][s] ----------------
__global__ __launch_bounds__(256) void k_transpose_v(const u16* __restrict__ V,
                                                     u16* __restrict__ Vt) {
  __shared__ u16 t[64][68];
  const int bh = blockIdx.z;
  const long s0 = (long)blockIdx.x * 64;
  const long d0 = (long)blockIdx.y * 64;
  const int tid = threadIdx.x;
  const long rowbase = (long)(bh >> 4) * 2048;
  const int hcol = (bh & 15) * 128;
#pragma unroll
  for (int i = 0; i < 4; ++i) {
    const int v = tid + i * 256;
    const int r = v >> 4, c4 = (v & 15) << 2;
    const u16x4 val = *(const u16x4*)&V[(rowbase + s0 + r) * 2048 + hcol + d0 + c4];
    *(u16x4*)&t[r][c4] = val;
  }
  __syncthreads();
#pragma unroll
  for (int i = 0; i < 4; ++i) {
    const int v = tid + i * 256;
    const int dr = v >> 4, s4 = (v & 15) << 2;
    u16x4 o;
    o.x = t[s4 + 0][dr]; o.y = t[s4 + 1][dr]; o.z = t[s4 + 2][dr]; o.w = t[s4 + 3][dr];
    *(u16x4*)&Vt[((long)bh * 128 + d0 + dr) * 2048 + s0 + s4] = o;
  }
}

// ---------------- causal flash attention: SWAPPED QK^T + dbuf + counted vmcnt ------
// R11 geometry (512 blocks, 4 waves x 16 q-rows, pass pairing (bx,31-bx), K/V dbuf,
// vmcnt(8), 2 blocks/CU). SWAPPED: st = mfma(kf, qf) -> D[kv][q]: each lane owns ONE
// q-row (q = q_lo + (lane&15)) with 16 kv values IN REGISTERS. Softmax row-reduce =
// in-reg chain + 2 shfl_xor (16,32) instead of 16 shfl instrs x2 -> removes ~28
// ds_bpermute (LDS-unit) ops per wave-step. m/l are per-lane scalars; alpha/inv are
// bridged to the O-accumulator layout (rows = fg*4+reg) via __shfl(x, fg*4+r).
__global__ __launch_bounds__(256, 2) void k_flash_attn(
    const u16* __restrict__ Q, const u16* __restrict__ K, const u16* __restrict__ Vt,
    u16* __restrict__ O)
{
  __shared__ alignas(16) u16 Kt[2][8192];    // [64 kv][128 d], swizzled
  __shared__ alignas(16) u16 Vtt[2][8192];   // [128 d][64 s], swizzled
  __shared__ alignas(16) u16 Plds[4][16][72];

  const int tid = threadIdx.x;
  const int lane = tid & 63, wid = tid >> 6;
  const int fr = lane & 15, fg = lane >> 4;

  // XCD map: all 16 blocks of one bh share L%32 -> same XCD (K/V L2-resident)
  const int L = blockIdx.x;
  const int bh = (L & 7) * 4 + ((L >> 3) & 3);
  const int bx = L >> 5;                     // 0..15

  const long rowbase = (long)(bh >> 4) * 2048;
  const int hcol = (bh & 15) * 128;
  const u16* Kg = K + rowbase * 2048 + hcol;
  const u16* Vg = Vt + (long)bh * 128 * 2048;
  const float scale2 = 0.08838834764831845f * 1.44269504089f;  // 1/sqrt(128)*log2(e)

  int kR[4], kC[4], vR[4], vC[4];
#pragma unroll
  for (int i = 0; i < 4; ++i) {
    const int g = (wid * 4 + i) * 64 + lane;
    kR[i] = g >> 4;                              // K: 16 chunks/row
    kC[i] = ((g & 15) ^ (kR[i] & 7)) << 3;
    vR[i] = g >> 3;                              // V: 8 chunks/row
    vC[i] = ((g & 7) ^ (vR[i] & 7)) << 3;
  }

  const int sw = fr & 7;
  int kbase[4], vbase[2];
#pragma unroll
  for (int c = 0; c < 4; ++c) kbase[c] = fr * 128 + (((c * 4 + fg) ^ sw) << 3);
#pragma unroll
  for (int kc = 0; kc < 2; ++kc) vbase[kc] = fr * 64 + (((kc * 4 + fg) ^ sw) << 3);

  for (int pass = 0; pass < 2; ++pass) {
    const int qblk = pass ? (31 - bx) : bx;
    const int n = qblk + 1;
    const int q_lo = qblk * 64 + wid * 16;
    const int qg = q_lo + fr;                    // this lane's q-row (swapped layout)

    bf16x8 qf[4];
#pragma unroll
    for (int c = 0; c < 4; ++c)
      qf[c] = *(const bf16x8*)&Q[(rowbase + q_lo + fr) * 2048 + hcol + c * 32 + fg * 8];

    f32x4 oacc[8] = {};
    float m_run = -1e30f, l_run = 0.0f;          // per-lane scalars (q = qg)

    // prologue: stage kv-tile 0 into buffer 0 (8 loads/thread)
#pragma unroll
    for (int i = 0; i < 4; ++i) {
      gload16(Kg + (long)kR[i] * 2048 + kC[i], &Kt[0][(wid * 4 + i) * 512]);
      gload16(Vg + (long)vR[i] * 2048 + vC[i], &Vtt[0][(wid * 4 + i) * 512]);
    }

    int cur = 0;
    for (int j = 0; j < n; ++j) {
      if (j + 1 < n) {
        const long kv = (long)(j + 1) * 64;
#pragma unroll
        for (int i = 0; i < 4; ++i) {
          gload16(Kg + (kv + kR[i]) * 2048 + kC[i], &Kt[cur ^ 1][(wid * 4 + i) * 512]);
          gload16(Vg + (long)vR[i] * 2048 + kv + vC[i], &Vtt[cur ^ 1][(wid * 4 + i) * 512]);
        }
        asm volatile("s_waitcnt vmcnt(8)" ::: "memory");   // tile j landed; j+1 in flight
      } else {
        asm volatile("s_waitcnt vmcnt(0)" ::: "memory");
      }
      __builtin_amdgcn_s_barrier();
      __builtin_amdgcn_sched_barrier(0);

      const int kvlo = j * 64;
      const bool skip = (kvlo >= q_lo + 16);
      if (!skip) {
        const bool needmask = (kvlo + 63 > q_lo);

        // ---- QK^T swapped: st[t] = K-tile x Q -> D[kv = t*16+fg*4+reg][q = fr] ----
        f32x4 st[4] = {};
        const u16* kt = Kt[cur];
#pragma unroll
        for (int t = 0; t < 4; ++t)
#pragma unroll
          for (int c = 0; c < 4; ++c) {
            const bf16x8 kf = *(const bf16x8*)&kt[kbase[c] + t * 2048];
            st[t] = __builtin_amdgcn_mfma_f32_16x16x32_bf16(kf, qf[c], st[t], 0, 0, 0);
          }

        // ---- scale/mask + row max (in-register; q is lane-local) ----
        float pmax = -1e30f;
        if (needmask) {
#pragma unroll
          for (int t = 0; t < 4; ++t)
#pragma unroll
            for (int r = 0; r < 4; ++r) {
              const int kg = kvlo + t * 16 + fg * 4 + r;
              const float v = (kg <= qg) ? st[t][r] * scale2 : -1e30f;
              st[t][r] = v;
              pmax = fmaxf(pmax, v);
            }
        } else {
#pragma unroll
          for (int t = 0; t < 4; ++t)
#pragma unroll
            for (int r = 0; r < 4; ++r) {
              const float v = st[t][r] * scale2;
              st[t][r] = v;
              pmax = fmaxf(pmax, v);
            }
        }
        pmax = fmaxf(pmax, __shfl_xor(pmax, 16));
        pmax = fmaxf(pmax, __shfl_xor(pmax, 32));

        // ---- defer-max rescale (THR=8 log2 units); alpha bridged to O layout ----
        if (!__all(pmax <= m_run + 8.f)) {
          const float nm = fmaxf(m_run, pmax);
          const float al = exp2f(m_run - nm);
          l_run *= al;
          m_run = nm;
          float alr[4];
#pragma unroll
          for (int r = 0; r < 4; ++r) alr[r] = __shfl(al, fg * 4 + r);
#pragma unroll
          for (int dt = 0; dt < 8; ++dt)
#pragma unroll
            for (int r = 0; r < 4; ++r) oacc[dt][r] *= alr[r];
        }

        // ---- P = exp2(s-m), row sum (in-register) ----
        float lsum = 0.f;
#pragma unroll
        for (int t = 0; t < 4; ++t)
#pragma unroll
          for (int r = 0; r < 4; ++r) {
            const float p = exp2f(st[t][r] - m_run);
            st[t][r] = p;
            lsum += p;
          }
        lsum += __shfl_xor(lsum, 16);
        lsum += __shfl_xor(lsum, 32);
        l_run += lsum;

        // ---- P -> per-wave LDS in A-operand layout: Plds[q][kv] ----
#pragma unroll
        for (int t = 0; t < 4; ++t)
#pragma unroll
          for (int r = 0; r < 4; ++r)
            Plds[wid][fr][t * 16 + fg * 4 + r] = f2bf(st[t][r]);
        asm volatile("s_waitcnt lgkmcnt(0)" ::: "memory");
        __builtin_amdgcn_sched_barrier(0);

        // ---- O += P * V (unchanged; D rows = q = fg*4+reg) ----
        const u16* vt = Vtt[cur];
#pragma unroll
        for (int kc = 0; kc < 2; ++kc) {
          const bf16x8 pf = *(const bf16x8*)&Plds[wid][fr][kc * 32 + fg * 8];
#pragma unroll
          for (int dt = 0; dt < 8; ++dt) {
            const bf16x8 vf = *(const bf16x8*)&vt[vbase[kc] + dt * 1024];
            oacc[dt] = __builtin_amdgcn_mfma_f32_16x16x32_bf16(pf, vf, oacc[dt], 0, 0, 0);
          }
        }
      }

      asm volatile("" ::: "memory");
      __builtin_amdgcn_s_barrier();          // all waves done reading buf[cur]
      cur ^= 1;
    }

    // epilogue: bridge 1/l to O layout (rows = fg*4+reg)
    const float li = 1.0f / l_run;
    float inv[4];
#pragma unroll
    for (int r = 0; r < 4; ++r) inv[r] = __shfl(li, fg * 4 + r);
#pragma unroll
    for (int dt = 0; dt < 8; ++dt)
#pragma unroll
      for (int r = 0; r < 4; ++r)
        O[(rowbase + q_lo + fg * 4 + r) * 2048 + hcol + dt * 16 + fr] = f2bf(oacc[dt][r] * inv[r]);
  }
}

extern "C" void kernel_launch(void* const* d_in, const int* in_sizes, int n_in,
                              void* d_out, int out_size, void* d_ws, size_t ws_size,
                              hipStream_t stream) {
  const float* x  = (const float*)d_in[0];
  const float* Wq = (const float*)d_in[1];
  const float* bq = (const float*)d_in[2];
  const float* Wk = (const float*)d_in[3];
  const float* bk = (const float*)d_in[4];
  const float* Wv = (const float*)d_in[5];
  const float* bv = (const float*)d_in[6];
  const float* Wo = (const float*)d_in[7];
  const float* bo = (const float*)d_in[8];
  float* out = (float*)d_out;

  char* ws = (char*)d_ws;
  const size_t SZ_X = 16777216;   // 8M bf16
  const size_t SZ_W = 8388608;    // 4M bf16
  u16* xb  = (u16*)(ws);
  u16* wqb = (u16*)(ws + SZ_X);                 // wq/wk/wv contiguous = [6144][2048]
  u16* wkb = (u16*)(ws + SZ_X + 1 * SZ_W);
  u16* wvb = (u16*)(ws + SZ_X + 2 * SZ_W);
  u16* wob = (u16*)(ws + SZ_X + 3 * SZ_W);
  u16* Qb  = (u16*)(ws + 1 * SZ_X + 4 * SZ_W);
  u16* Kb  = (u16*)(ws + 2 * SZ_X + 4 * SZ_W);
  u16* Vb  = (u16*)(ws + 3 * SZ_X + 4 * SZ_W);
  u16* Vtb = (u16*)(ws + 4 * SZ_X + 4 * SZ_W);
  u16* Ob  = Vb;   // V dead after transpose; reuse for attention output

  k_f2bf5<<<dim3(1024, 5), 256, 0, stream>>>(x, Wq, Wk, Wv, Wo,
                                             xb, wqb, wkb, wvb, wob,
                                             8388608 / 4, 4194304 / 4);

  // fused QKV: M=4096 x N=6144 x K=2048; 32x48 = 1536 blocks, ~4 blocks/CU resident
  k_gemm12<0><<<1536, 256, 0, stream>>>(xb, wqb, bq, bk, bv, Qb, Kb, Vb, nullptr, 32);

  k_transpose_v<<<dim3(32, 2, 32), 256, 0, stream>>>(Vb, Vtb);

  k_flash_attn<<<512, 256, 0, stream>>>(Qb, Kb, Vtb, Ob);

  // output projection (fp32 out): 32x16 = 512 blocks
  k_gemm12<1><<<512, 256, 0, stream>>>(Ob, wob, bo, bo, bo, nullptr, nullptr, nullptr, out, 32);
}